// Round 2
// baseline (335.330 us; speedup 1.0000x reference)
//
#include <hip/hip_runtime.h>
#include <cmath>

typedef __attribute__((ext_vector_type(8))) short short8;
typedef __attribute__((ext_vector_type(4))) float f32x4;
typedef __attribute__((ext_vector_type(4))) unsigned short us4;
typedef unsigned short u16;

#define BATCH 8192
#define HDIM  256
static constexpr size_t BH = (size_t)BATCH * HDIM;  // 2,097,152

__device__ __forceinline__ u16 f2bf(float f) {
    union { float f; unsigned u; } v; v.f = f;
    unsigned r = v.u + 0x7FFFu + ((v.u >> 16) & 1u);
    return (u16)(r >> 16);
}
__device__ __forceinline__ float bf2f(u16 u) {
    union { unsigned u; float f; } v; v.u = ((unsigned)u) << 16;
    return v.f;
}
__device__ __forceinline__ float wred(float v) {
#pragma unroll
    for (int o = 32; o > 0; o >>= 1) v += __shfl_xor(v, o);
    return v;
}
__device__ __forceinline__ float sigmoidf_(float x) {
    return 1.f / (1.f + __expf(-x));
}

// ---------------- weight conversion: pack all needed weights to bf16 ----------------
// dst layout (u16 units, 65536 per chunk):
//  c0: embed_w | c1..4: wtn[l] | c5..8: wsn[l] | c9..12: wt[l][512:768]
//  c13..16: ws[l][0:256] | c17..20: ws[l][512:768] | c21: out_w
__global__ __launch_bounds__(256) void convert_weights(
    const float* __restrict__ embed_w, const float* __restrict__ wtn,
    const float* __restrict__ wsn, const float* __restrict__ wt,
    const float* __restrict__ ws, const float* __restrict__ out_w,
    u16* __restrict__ dst)
{
    int idx = blockIdx.x * 256 + threadIdx.x;
    int e = idx * 4;
    if (e >= 22 * 65536) return;
    int c = e >> 16, o = e & 65535;
    const float* src;
    if (c == 0)      src = embed_w + o;
    else if (c < 5)  src = wtn + (size_t)(c - 1) * 65536 + o;
    else if (c < 9)  src = wsn + (size_t)(c - 5) * 65536 + o;
    else if (c < 13) src = wt + (size_t)(c - 9) * 768 * 256 + 512 * 256 + o;
    else if (c < 17) src = ws + (size_t)(c - 13) * 768 * 256 + o;
    else if (c < 21) src = ws + (size_t)(c - 17) * 768 * 256 + 512 * 256 + o;
    else             src = out_w + o;
    f32x4 v = *(const f32x4*)src;
    us4 r;
#pragma unroll
    for (int j = 0; j < 4; ++j) r[j] = f2bf(v[j]);
    *(us4*)(dst + e) = r;
}

// ---------------- full-N GEMM: C[M,256] = A[M,256] @ W[256,256]^T + bias ----------------
// block = 256 thr (4 waves), tile 64 rows x 256 cols; wave w -> cols 64w..64w+63.
// A read exactly once from HBM (waves share A via L1).
// ACT==0: store bf16; ACT==1: store f32 tanh (final output).
template<bool A_F32, int ACT>
__global__ __launch_bounds__(256) void gemm_fullN(
    const void* __restrict__ Ap, const u16* __restrict__ W,
    const float* __restrict__ bias, void* __restrict__ Cp)
{
    const int lane = threadIdx.x & 63;
    const int wave = threadIdx.x >> 6;
    const int row0 = blockIdx.x * 64;
    const int n0 = wave * 64;
    const int lr = lane & 15;
    const int kg = lane >> 4;

    f32x4 acc[4][4] = {};
    for (int k0 = 0; k0 < 256; k0 += 32) {
        int k = k0 + kg * 8;
        short8 a[4], b[4];
        if constexpr (A_F32) {
            const float* A = (const float*)Ap;
#pragma unroll
            for (int mt = 0; mt < 4; ++mt) {
                const float* p = A + (size_t)(row0 + mt * 16 + lr) * 256 + k;
                f32x4 lo = *(const f32x4*)p;
                f32x4 hi = *(const f32x4*)(p + 4);
                short8 t;
                t[0] = (short)f2bf(lo[0]); t[1] = (short)f2bf(lo[1]);
                t[2] = (short)f2bf(lo[2]); t[3] = (short)f2bf(lo[3]);
                t[4] = (short)f2bf(hi[0]); t[5] = (short)f2bf(hi[1]);
                t[6] = (short)f2bf(hi[2]); t[7] = (short)f2bf(hi[3]);
                a[mt] = t;
            }
        } else {
            const u16* A = (const u16*)Ap;
#pragma unroll
            for (int mt = 0; mt < 4; ++mt)
                a[mt] = *(const short8*)(A + (size_t)(row0 + mt * 16 + lr) * 256 + k);
        }
#pragma unroll
        for (int nt = 0; nt < 4; ++nt)
            b[nt] = *(const short8*)(W + (size_t)(n0 + nt * 16 + lr) * 256 + k);
#pragma unroll
        for (int mt = 0; mt < 4; ++mt)
#pragma unroll
            for (int nt = 0; nt < 4; ++nt)
                acc[mt][nt] = __builtin_amdgcn_mfma_f32_16x16x32_bf16(a[mt], b[nt], acc[mt][nt], 0, 0, 0);
    }
#pragma unroll
    for (int nt = 0; nt < 4; ++nt) {
        int n = n0 + nt * 16 + lr;
        float bn = bias[n];
#pragma unroll
        for (int mt = 0; mt < 4; ++mt) {
            int m0 = row0 + mt * 16 + kg * 4;
#pragma unroll
            for (int r = 0; r < 4; ++r) {
                float v = acc[mt][nt][r] + bn;
                if constexpr (ACT == 0) ((u16*)Cp)[(size_t)(m0 + r) * 256 + n] = f2bf(v);
                else                    ((float*)Cp)[(size_t)(m0 + r) * 256 + n] = tanhf(v);
            }
        }
    }
}

// ---------------- fused full layer ----------------
// Per block: 16 batch rows, full H. 256 thr = 4 waves.
// Phase 1: s_next = S@wsn^T+bsn, t_next = T_last@wtn^T+btn  -> LDS (f32)
// Phase 2: temporal + spatial attention + gating -> T_fus/S_fus in LDS (bf16)
// Phase 3: t_s/s_g/s_s triple GEMM + gated combine -> S_hist[layer+1] (bf16)
#define SNP 260   // f32 LDS row stride (padded; 1040 B, 16B-aligned)
#define TFP 264   // u16 LDS row stride (padded; 528 B, 16B-aligned)
__global__ __launch_bounds__(256) void layer_fused(
    const float* __restrict__ t_att, const float* __restrict__ s_att,
    u16* __restrict__ S_hist, const u16* __restrict__ Wbf,
    const float* __restrict__ btn, const float* __restrict__ bsn,
    const float* __restrict__ bt, const float* __restrict__ bs,
    int layer)
{
    __shared__ float sn_lds[16 * SNP];
    __shared__ float tn_lds[16 * SNP];
    __shared__ u16   tf_lds[16 * TFP];
    __shared__ u16   sf_lds[16 * TFP];

    const int lane = threadIdx.x & 63;
    const int wave = threadIdx.x >> 6;
    const int lr = lane & 15;
    const int kg = lane >> 4;
    const int row0 = blockIdx.x * 16;

    // ---- Phase 1: dual GEMM (16x256x256 each) ----
    {
        const int g = wave >> 1;          // 0: s_next, 1: t_next
        const int n0 = (wave & 1) * 128;  // column half
        const u16* Wm = Wbf + (size_t)((g ? 1 : 5) + layer) * 65536;
        const float* bias = (g ? btn : bsn) + layer * 256;
        const u16* Abf = S_hist + (size_t)layer * BH;
        const float* Af = t_att + ((size_t)layer * 8 + 7) * BH;

        f32x4 acc[8] = {};
        for (int k0 = 0; k0 < 256; k0 += 32) {
            int k = k0 + kg * 8;
            short8 a;
            if (g == 0) {
                a = *(const short8*)(Abf + (size_t)(row0 + lr) * 256 + k);
            } else {
                const float* p = Af + (size_t)(row0 + lr) * 256 + k;
                f32x4 lo = *(const f32x4*)p;
                f32x4 hi = *(const f32x4*)(p + 4);
                short8 t;
                t[0] = (short)f2bf(lo[0]); t[1] = (short)f2bf(lo[1]);
                t[2] = (short)f2bf(lo[2]); t[3] = (short)f2bf(lo[3]);
                t[4] = (short)f2bf(hi[0]); t[5] = (short)f2bf(hi[1]);
                t[6] = (short)f2bf(hi[2]); t[7] = (short)f2bf(hi[3]);
                a = t;
            }
#pragma unroll
            for (int nf = 0; nf < 8; ++nf) {
                short8 b = *(const short8*)(Wm + (size_t)(n0 + nf * 16 + lr) * 256 + k);
                acc[nf] = __builtin_amdgcn_mfma_f32_16x16x32_bf16(a, b, acc[nf], 0, 0, 0);
            }
        }
        float* dst = g ? tn_lds : sn_lds;
#pragma unroll
        for (int nf = 0; nf < 8; ++nf) {
            int n = n0 + nf * 16 + lr;
            float bn = bias[n];
#pragma unroll
            for (int r = 0; r < 4; ++r)
                dst[(kg * 4 + r) * SNP + n] = acc[nf][r] + bn;
        }
    }
    __syncthreads();

    // ---- Phase 2: attention + gating (wave w handles rows 4w..4w+3) ----
    {
        const float scale = 0.0625f;  // 1/sqrt(256)
        for (int rr = wave * 4; rr < wave * 4 + 4; ++rr) {
            const int b = row0 + rr;
            const size_t ro = (size_t)b * 256 + lane * 4;

            f32x4 snv = *(const f32x4*)(sn_lds + rr * SNP + lane * 4);
            f32x4 tnv = *(const f32x4*)(tn_lds + rr * SNP + lane * 4);
            us4 scu = *(const us4*)(S_hist + (size_t)layer * BH + ro);
            float Sc[4];
#pragma unroll
            for (int j = 0; j < 4; ++j) Sc[j] = bf2f(scu[j]);

            const float* ta = t_att + (size_t)layer * 8 * BH + ro;
            const float* sa = s_att + (size_t)layer * 8 * BH + ro;

            // temporal logits: keys = s_att[i,1:] ++ [S]
            float lt[8];
#pragma unroll
            for (int kk = 0; kk < 7; ++kk) {
                f32x4 v = *(const f32x4*)(sa + (size_t)(kk + 1) * BH);
                lt[kk] = wred(v[0] * snv[0] + v[1] * snv[1] + v[2] * snv[2] + v[3] * snv[3]) * scale;
            }
            lt[7] = wred(Sc[0] * snv[0] + Sc[1] * snv[1] + Sc[2] * snv[2] + Sc[3] * snv[3]) * scale;

            float m = lt[0];
#pragma unroll
            for (int kk = 1; kk < 8; ++kk) m = fmaxf(m, lt[kk]);
            float w8[8], den = 0.f;
#pragma unroll
            for (int kk = 0; kk < 8; ++kk) { w8[kk] = __expf(lt[kk] - m); den += w8[kk]; }
            float inv = 1.f / den;

            // T_trend + T_fusion
            float Tt[4] = {0.f, 0.f, 0.f, 0.f}, Tl[4];
#pragma unroll
            for (int kk = 0; kk < 8; ++kk) {
                f32x4 v = *(const f32x4*)(ta + (size_t)kk * BH);
#pragma unroll
                for (int j = 0; j < 4; ++j) Tt[j] += w8[kk] * v[j];
                if (kk == 7) { Tl[0] = v[0]; Tl[1] = v[1]; Tl[2] = v[2]; Tl[3] = v[3]; }
            }
            us4 ot;
#pragma unroll
            for (int j = 0; j < 4; ++j) {
                float g = sigmoidf_(tnv[j]);
                ot[j] = f2bf(Tl[j] * g + (1.f - g) * Tt[j] * inv);
            }
            *(us4*)(tf_lds + rr * TFP + lane * 4) = ot;

            // spatial: t_sp = [zeros x (7-layer), t_att[0,7]..t_att[layer,7]]
            //          s_sp = [zeros x (7-layer), S_hist[0]..S_hist[layer]]
            float msx = 0.f;
            float dens = (float)(7 - layer);
            float St[4] = {0.f, 0.f, 0.f, 0.f};
            for (int jj = 0; jj <= layer; ++jj) {
                f32x4 v = *(const f32x4*)(t_att + ((size_t)jj * 8 + 7) * BH + ro);
                float p = wred(v[0] * tnv[0] + v[1] * tnv[1] + v[2] * tnv[2] + v[3] * tnv[3]) * scale;
                us4 shu = *(const us4*)(S_hist + (size_t)jj * BH + ro);
                if (p > msx) {  // wave-uniform (p is post-reduction)
                    float c = __expf(msx - p);
                    dens *= c; St[0] *= c; St[1] *= c; St[2] *= c; St[3] *= c;
                    msx = p;
                }
                float w = __expf(p - msx);
                dens += w;
#pragma unroll
                for (int j = 0; j < 4; ++j) St[j] += w * bf2f(shu[j]);
            }
            float invs = 1.f / dens;
            us4 os;
#pragma unroll
            for (int j = 0; j < 4; ++j) {
                float g = sigmoidf_(snv[j]);
                os[j] = f2bf(Sc[j] * g + (1.f - g) * St[j] * invs);
            }
            *(us4*)(sf_lds + rr * TFP + lane * 4) = os;
        }
    }
    __syncthreads();

    // ---- Phase 3: triple GEMM + gated combine (wave w -> cols 64w..64w+63) ----
    {
        const int n0 = wave * 64;
        const u16* Wt3 = Wbf + (size_t)(9  + layer) * 65536;
        const u16* Ws1 = Wbf + (size_t)(13 + layer) * 65536;
        const u16* Ws3 = Wbf + (size_t)(17 + layer) * 65536;

        f32x4 accT[4] = {}, accG[4] = {}, accS[4] = {};
        for (int k0 = 0; k0 < 256; k0 += 32) {
            int k = k0 + kg * 8;
            short8 at = *(const short8*)(tf_lds + lr * TFP + k);
            short8 as = *(const short8*)(sf_lds + lr * TFP + k);
#pragma unroll
            for (int nf = 0; nf < 4; ++nf) {
                size_t wo = (size_t)(n0 + nf * 16 + lr) * 256 + k;
                accT[nf] = __builtin_amdgcn_mfma_f32_16x16x32_bf16(at, *(const short8*)(Wt3 + wo), accT[nf], 0, 0, 0);
                accG[nf] = __builtin_amdgcn_mfma_f32_16x16x32_bf16(as, *(const short8*)(Ws1 + wo), accG[nf], 0, 0, 0);
                accS[nf] = __builtin_amdgcn_mfma_f32_16x16x32_bf16(as, *(const short8*)(Ws3 + wo), accS[nf], 0, 0, 0);
            }
        }
        u16* Sout = S_hist + (size_t)(layer + 1) * BH;
        const float* b1 = bt + layer * 768 + 512;
        const float* b2 = bs + layer * 768;
        const float* b3 = bs + layer * 768 + 512;
#pragma unroll
        for (int nf = 0; nf < 4; ++nf) {
            int n = n0 + nf * 16 + lr;
            float bb1 = b1[n], bb2 = b2[n], bb3 = b3[n];
#pragma unroll
            for (int r = 0; r < 4; ++r) {
                float gv = sigmoidf_(accG[nf][r] + bb2);
                float v = gv * (accS[nf][r] + bb3) + (1.f - gv) * (accT[nf][r] + bb1);
                Sout[(size_t)(row0 + kg * 4 + r) * 256 + n] = f2bf(v);
            }
        }
    }
}

extern "C" void kernel_launch(void* const* d_in, const int* in_sizes, int n_in,
                              void* d_out, int out_size, void* d_ws, size_t ws_size,
                              hipStream_t stream)
{
    (void)in_sizes; (void)n_in; (void)out_size; (void)ws_size;
    const float* x       = (const float*)d_in[0];
    const float* t_att   = (const float*)d_in[1];
    const float* s_att   = (const float*)d_in[2];
    const float* embed_w = (const float*)d_in[3];
    const float* embed_b = (const float*)d_in[4];
    const float* wtn     = (const float*)d_in[5];
    const float* btn     = (const float*)d_in[6];
    const float* wsn     = (const float*)d_in[7];
    const float* bsn     = (const float*)d_in[8];
    const float* wt      = (const float*)d_in[9];
    const float* bt      = (const float*)d_in[10];
    const float* ws_in   = (const float*)d_in[11];
    const float* bs      = (const float*)d_in[12];
    const float* out_w   = (const float*)d_in[13];
    const float* out_b   = (const float*)d_in[14];

    u16* wsp    = (u16*)d_ws;
    u16* Wbf    = wsp;                       // 22 * 65536 u16
    u16* S_hist = wsp + (size_t)22 * 65536;  // 5 * BH u16

    convert_weights<<<1408, 256, 0, stream>>>(embed_w, wtn, wsn, wt, ws_in, out_w, Wbf);

    // S0 = x @ embed_w^T + embed_b
    gemm_fullN<true, 0><<<BATCH / 64, 256, 0, stream>>>(x, Wbf, embed_b, S_hist);

    for (int i = 0; i < 4; ++i)
        layer_fused<<<BATCH / 16, 256, 0, stream>>>(t_att, s_att, S_hist, Wbf,
                                                    btn, bsn, bt, bs, i);

    // out = tanh(S @ out_w^T + out_b), f32
    gemm_fullN<false, 1><<<BATCH / 64, 256, 0, stream>>>(
        S_hist + (size_t)4 * BH, Wbf + (size_t)21 * 65536, out_b, d_out);
}

// Round 3
// 284.377 us; speedup vs baseline: 1.1792x; 1.1792x over previous
//
#include <hip/hip_runtime.h>
#include <cmath>

typedef __attribute__((ext_vector_type(8))) short short8;
typedef __attribute__((ext_vector_type(4))) float f32x4;
typedef __attribute__((ext_vector_type(4))) unsigned short us4;
typedef unsigned short u16;

#define BATCH 8192
#define HDIM  256
static constexpr size_t BH = (size_t)BATCH * HDIM;  // 2,097,152

__device__ __forceinline__ u16 f2bf(float f) {
    union { float f; unsigned u; } v; v.f = f;
    unsigned r = v.u + 0x7FFFu + ((v.u >> 16) & 1u);
    return (u16)(r >> 16);
}
__device__ __forceinline__ float bf2f(u16 u) {
    union { unsigned u; float f; } v; v.u = ((unsigned)u) << 16;
    return v.f;
}
__device__ __forceinline__ float wred(float v) {
#pragma unroll
    for (int o = 32; o > 0; o >>= 1) v += __shfl_xor(v, o);
    return v;
}
__device__ __forceinline__ float sigmoidf_(float x) {
    return 1.f / (1.f + __expf(-x));
}
__device__ __forceinline__ short8 cvt8(const float* p) {
    f32x4 lo = *(const f32x4*)p, hi = *(const f32x4*)(p + 4);
    short8 t;
    t[0] = (short)f2bf(lo[0]); t[1] = (short)f2bf(lo[1]);
    t[2] = (short)f2bf(lo[2]); t[3] = (short)f2bf(lo[3]);
    t[4] = (short)f2bf(hi[0]); t[5] = (short)f2bf(hi[1]);
    t[6] = (short)f2bf(hi[2]); t[7] = (short)f2bf(hi[3]);
    return t;
}

// ---------------- weight conversion: pack all needed weights to bf16 ----------------
// dst layout (u16 units, 65536 per chunk):
//  c0: embed_w | c1..4: wtn[l] | c5..8: wsn[l] | c9..12: wt[l][512:768]
//  c13..16: ws[l][0:256] | c17..20: ws[l][512:768] | c21: out_w
__global__ __launch_bounds__(256) void convert_weights(
    const float* __restrict__ embed_w, const float* __restrict__ wtn,
    const float* __restrict__ wsn, const float* __restrict__ wt,
    const float* __restrict__ ws, const float* __restrict__ out_w,
    u16* __restrict__ dst)
{
    int idx = blockIdx.x * 256 + threadIdx.x;
    int e = idx * 4;
    if (e >= 22 * 65536) return;
    int c = e >> 16, o = e & 65535;
    const float* src;
    if (c == 0)      src = embed_w + o;
    else if (c < 5)  src = wtn + (size_t)(c - 1) * 65536 + o;
    else if (c < 9)  src = wsn + (size_t)(c - 5) * 65536 + o;
    else if (c < 13) src = wt + (size_t)(c - 9) * 768 * 256 + 512 * 256 + o;
    else if (c < 17) src = ws + (size_t)(c - 13) * 768 * 256 + o;
    else if (c < 21) src = ws + (size_t)(c - 17) * 768 * 256 + 512 * 256 + o;
    else             src = out_w + o;
    f32x4 v = *(const f32x4*)src;
    us4 r;
#pragma unroll
    for (int j = 0; j < 4; ++j) r[j] = f2bf(v[j]);
    *(us4*)(dst + e) = r;
}

// ---------------- mega kernel: embed + 4 layers + out, all row-local ----------------
// 512 threads (8 waves), 16 batch rows per block, grid 512. All per-row state
// (S history, s_next/t_next, T_fus/S_fus) lives in LDS; HBM carries only the
// inherent t_att/s_att streams + x + out + weights (via L2).
#define PAD 264  // u16 row stride (528 B: 16B-aligned, breaks 512B bank pattern)
__global__ __launch_bounds__(512, 4) void stau_mega(
    const float* __restrict__ x,
    const float* __restrict__ t_att, const float* __restrict__ s_att,
    const u16* __restrict__ Wbf,
    const float* __restrict__ embed_b,
    const float* __restrict__ btn, const float* __restrict__ bsn,
    const float* __restrict__ bt, const float* __restrict__ bs,
    const float* __restrict__ out_b,
    float* __restrict__ outp)
{
    __shared__ __align__(16) u16 S_lds[5][16][PAD];  // S history (bf16)
    __shared__ __align__(16) u16 sn_lds[16][PAD];    // s_next (bf16)
    __shared__ __align__(16) u16 tn_lds[16][PAD];    // t_next (bf16)
    __shared__ __align__(16) u16 tf_lds[16][PAD];    // T_fusion (bf16)
    __shared__ __align__(16) u16 sf_lds[16][PAD];    // S_fusion (bf16)

    const int lane = threadIdx.x & 63;
    const int wave = threadIdx.x >> 6;  // 0..7
    const int lr = lane & 15;
    const int kg = lane >> 4;
    const int row0 = blockIdx.x * 16;
    const float scale = 0.0625f;  // 1/sqrt(256)

    // ---- embed: S0 = x @ embed_w^T + embed_b (wave w -> cols 32w..32w+31) ----
    {
        const int n0 = wave * 32;
        f32x4 acc[2] = {};
        for (int k0 = 0; k0 < 256; k0 += 32) {
            int k = k0 + kg * 8;
            short8 a = cvt8(x + (size_t)(row0 + lr) * 256 + k);
#pragma unroll
            for (int nf = 0; nf < 2; ++nf) {
                short8 b = *(const short8*)(Wbf + (size_t)(n0 + nf * 16 + lr) * 256 + k);
                acc[nf] = __builtin_amdgcn_mfma_f32_16x16x32_bf16(a, b, acc[nf], 0, 0, 0);
            }
        }
#pragma unroll
        for (int nf = 0; nf < 2; ++nf) {
            int n = n0 + nf * 16 + lr;
            float bn = embed_b[n];
#pragma unroll
            for (int r = 0; r < 4; ++r)
                S_lds[0][kg * 4 + r][n] = f2bf(acc[nf][r] + bn);
        }
    }
    __syncthreads();

    for (int i = 0; i < 4; ++i) {
        // ---- phase 1: s_next (waves 0-3) / t_next (waves 4-7), 64 cols each ----
        {
            const int g = wave >> 2;          // 0: s_next, 1: t_next
            const int n0 = (wave & 3) * 64;
            const u16* Wm = Wbf + (size_t)((g ? 1 : 5) + i) * 65536;
            const float* bias = (g ? btn : bsn) + i * 256;
            f32x4 acc[4] = {};
            for (int k0 = 0; k0 < 256; k0 += 32) {
                int k = k0 + kg * 8;
                short8 a;
                if (g == 0) a = *(const short8*)(&S_lds[i][lr][k]);
                else        a = cvt8(t_att + ((size_t)i * 8 + 7) * BH + (size_t)(row0 + lr) * 256 + k);
#pragma unroll
                for (int nf = 0; nf < 4; ++nf) {
                    short8 b = *(const short8*)(Wm + (size_t)(n0 + nf * 16 + lr) * 256 + k);
                    acc[nf] = __builtin_amdgcn_mfma_f32_16x16x32_bf16(a, b, acc[nf], 0, 0, 0);
                }
            }
            u16 (*dst)[PAD] = g ? tn_lds : sn_lds;
#pragma unroll
            for (int nf = 0; nf < 4; ++nf) {
                int n = n0 + nf * 16 + lr;
                float bn = bias[n];
#pragma unroll
                for (int r = 0; r < 4; ++r)
                    dst[kg * 4 + r][n] = f2bf(acc[nf][r] + bn);
            }
        }
        __syncthreads();

        // ---- phase 2: attention + gating (wave w -> rows 2w, 2w+1) ----
        for (int rr = wave * 2; rr < wave * 2 + 2; ++rr) {
            const size_t ro = (size_t)(row0 + rr) * 256 + lane * 4;
            us4 snu = *(const us4*)&sn_lds[rr][lane * 4];
            us4 tnu = *(const us4*)&tn_lds[rr][lane * 4];
            us4 scu = *(const us4*)&S_lds[i][rr][lane * 4];
            float sn[4], tn[4], Sc[4];
#pragma unroll
            for (int j = 0; j < 4; ++j) { sn[j] = bf2f(snu[j]); tn[j] = bf2f(tnu[j]); Sc[j] = bf2f(scu[j]); }

            const float* sa = s_att + (size_t)i * 8 * BH + ro;
            const float* ta = t_att + (size_t)i * 8 * BH + ro;

            // temporal logits: keys = s_att[i,1:] ++ [S]
            float lt[8];
#pragma unroll
            for (int kk = 0; kk < 7; ++kk) {
                f32x4 v = *(const f32x4*)(sa + (size_t)(kk + 1) * BH);
                lt[kk] = wred(v[0] * sn[0] + v[1] * sn[1] + v[2] * sn[2] + v[3] * sn[3]) * scale;
            }
            lt[7] = wred(Sc[0] * sn[0] + Sc[1] * sn[1] + Sc[2] * sn[2] + Sc[3] * sn[3]) * scale;

            float m = lt[0];
#pragma unroll
            for (int kk = 1; kk < 8; ++kk) m = fmaxf(m, lt[kk]);
            float w8[8], den = 0.f;
#pragma unroll
            for (int kk = 0; kk < 8; ++kk) { w8[kk] = __expf(lt[kk] - m); den += w8[kk]; }
            float inv = 1.f / den;

            // T_trend + T_fusion
            float Tt[4] = {0.f, 0.f, 0.f, 0.f}, Tl[4];
#pragma unroll
            for (int kk = 0; kk < 8; ++kk) {
                f32x4 v = *(const f32x4*)(ta + (size_t)kk * BH);
#pragma unroll
                for (int j = 0; j < 4; ++j) Tt[j] += w8[kk] * v[j];
                if (kk == 7) { Tl[0] = v[0]; Tl[1] = v[1]; Tl[2] = v[2]; Tl[3] = v[3]; }
            }
            us4 ot;
#pragma unroll
            for (int j = 0; j < 4; ++j) {
                float g = sigmoidf_(tn[j]);
                ot[j] = f2bf(Tl[j] * g + (1.f - g) * Tt[j] * inv);
            }
            *(us4*)&tf_lds[rr][lane * 4] = ot;

            // spatial: t_sp = [zeros x (7-i), t_att[0,7]..t_att[i,7]]
            //          s_sp = [zeros x (7-i), S_hist[0]..S_hist[i]]
            float msx = 0.f;
            float dens = (float)(7 - i);
            float St[4] = {0.f, 0.f, 0.f, 0.f};
            for (int jj = 0; jj <= i; ++jj) {
                f32x4 v = *(const f32x4*)(t_att + ((size_t)jj * 8 + 7) * BH + ro);
                float p = wred(v[0] * tn[0] + v[1] * tn[1] + v[2] * tn[2] + v[3] * tn[3]) * scale;
                us4 shu = *(const us4*)&S_lds[jj][rr][lane * 4];
                if (p > msx) {  // wave-uniform (p is post-reduction)
                    float c = __expf(msx - p);
                    dens *= c; St[0] *= c; St[1] *= c; St[2] *= c; St[3] *= c;
                    msx = p;
                }
                float w = __expf(p - msx);
                dens += w;
#pragma unroll
                for (int j = 0; j < 4; ++j) St[j] += w * bf2f(shu[j]);
            }
            float invs = 1.f / dens;
            us4 os;
#pragma unroll
            for (int j = 0; j < 4; ++j) {
                float g = sigmoidf_(sn[j]);
                os[j] = f2bf(Sc[j] * g + (1.f - g) * St[j] * invs);
            }
            *(us4*)&sf_lds[rr][lane * 4] = os;
        }
        __syncthreads();

        // ---- phase 3: triple GEMM + gated combine (wave w -> cols 32w..32w+31) ----
        {
            const int n0 = wave * 32;
            const u16* Wt3 = Wbf + (size_t)(9  + i) * 65536;
            const u16* Ws1 = Wbf + (size_t)(13 + i) * 65536;
            const u16* Ws3 = Wbf + (size_t)(17 + i) * 65536;
            f32x4 aT[2] = {}, aG[2] = {}, aS[2] = {};
            for (int k0 = 0; k0 < 256; k0 += 32) {
                int k = k0 + kg * 8;
                short8 at = *(const short8*)(&tf_lds[lr][k]);
                short8 as = *(const short8*)(&sf_lds[lr][k]);
#pragma unroll
                for (int nf = 0; nf < 2; ++nf) {
                    size_t wo = (size_t)(n0 + nf * 16 + lr) * 256 + k;
                    aT[nf] = __builtin_amdgcn_mfma_f32_16x16x32_bf16(at, *(const short8*)(Wt3 + wo), aT[nf], 0, 0, 0);
                    aG[nf] = __builtin_amdgcn_mfma_f32_16x16x32_bf16(as, *(const short8*)(Ws1 + wo), aG[nf], 0, 0, 0);
                    aS[nf] = __builtin_amdgcn_mfma_f32_16x16x32_bf16(as, *(const short8*)(Ws3 + wo), aS[nf], 0, 0, 0);
                }
            }
            const float* b1 = bt + i * 768 + 512;
            const float* b2 = bs + i * 768;
            const float* b3 = bs + i * 768 + 512;
#pragma unroll
            for (int nf = 0; nf < 2; ++nf) {
                int n = n0 + nf * 16 + lr;
                float bb1 = b1[n], bb2 = b2[n], bb3 = b3[n];
#pragma unroll
                for (int r = 0; r < 4; ++r) {
                    float gv = sigmoidf_(aG[nf][r] + bb2);
                    float v = gv * (aS[nf][r] + bb3) + (1.f - gv) * (aT[nf][r] + bb1);
                    S_lds[i + 1][kg * 4 + r][n] = f2bf(v);
                }
            }
        }
        __syncthreads();
    }

    // ---- out = tanh(S4 @ out_w^T + out_b), f32 ----
    {
        const int n0 = wave * 32;
        const u16* Wo = Wbf + (size_t)21 * 65536;
        f32x4 acc[2] = {};
        for (int k0 = 0; k0 < 256; k0 += 32) {
            int k = k0 + kg * 8;
            short8 a = *(const short8*)(&S_lds[4][lr][k]);
#pragma unroll
            for (int nf = 0; nf < 2; ++nf) {
                short8 b = *(const short8*)(Wo + (size_t)(n0 + nf * 16 + lr) * 256 + k);
                acc[nf] = __builtin_amdgcn_mfma_f32_16x16x32_bf16(a, b, acc[nf], 0, 0, 0);
            }
        }
#pragma unroll
        for (int nf = 0; nf < 2; ++nf) {
            int n = n0 + nf * 16 + lr;
            float bn = out_b[n];
#pragma unroll
            for (int r = 0; r < 4; ++r)
                outp[(size_t)(row0 + kg * 4 + r) * 256 + n] = tanhf(acc[nf][r] + bn);
        }
    }
}

extern "C" void kernel_launch(void* const* d_in, const int* in_sizes, int n_in,
                              void* d_out, int out_size, void* d_ws, size_t ws_size,
                              hipStream_t stream)
{
    (void)in_sizes; (void)n_in; (void)out_size; (void)ws_size;
    const float* x       = (const float*)d_in[0];
    const float* t_att   = (const float*)d_in[1];
    const float* s_att   = (const float*)d_in[2];
    const float* embed_w = (const float*)d_in[3];
    const float* embed_b = (const float*)d_in[4];
    const float* wtn     = (const float*)d_in[5];
    const float* btn     = (const float*)d_in[6];
    const float* wsn     = (const float*)d_in[7];
    const float* bsn     = (const float*)d_in[8];
    const float* wt      = (const float*)d_in[9];
    const float* bt      = (const float*)d_in[10];
    const float* ws_in   = (const float*)d_in[11];
    const float* bs      = (const float*)d_in[12];
    const float* out_w   = (const float*)d_in[13];
    const float* out_b   = (const float*)d_in[14];

    u16* Wbf = (u16*)d_ws;  // 22 * 65536 u16 = 2.88 MB

    convert_weights<<<1408, 256, 0, stream>>>(embed_w, wtn, wsn, wt, ws_in, out_w, Wbf);

    stau_mega<<<BATCH / 16, 512, 0, stream>>>(
        x, t_att, s_att, Wbf, embed_b, btn, bsn, bt, bs, out_b, (float*)d_out);
}